// Round 5
// baseline (2768.164 us; speedup 1.0000x reference)
//
#include <hip/hip_runtime.h>
#include <hip/hip_bf16.h>

typedef unsigned short u16;
typedef unsigned int u32;
typedef __attribute__((ext_vector_type(8))) short short8;
typedef __attribute__((ext_vector_type(4))) float f32x4;
typedef __attribute__((ext_vector_type(2))) float f32x2;

#define NB 32
#define NC_ 512
#define HW 1024
#define NE 256
#define NA 32
#define NR 24
#define PW_ 256
#define MLAN 128
#define NV 56  // Lanczos vectors cached in LDS (f32)

__device__ inline float b2f(u16 u) { return __uint_as_float(((u32)u) << 16); }
__device__ inline u16 f2b(float f) {
    u32 x = __float_as_uint(f);
    u32 r = x + 0x7FFFu + ((x >> 16) & 1u);
    return (u16)(r >> 16);
}
__device__ inline float gelu_exact(float x) {
    return 0.5f * x * (1.0f + erff(x * 0.70710678118654752f));
}
__device__ inline float sigmoidf_(float x) { return 1.0f / (1.0f + expf(-x)); }

template <int NW>
__device__ inline float block_reduce_sum(float x, volatile float* red) {
#pragma unroll
    for (int m = 32; m >= 1; m >>= 1) x += __shfl_xor(x, m);
    const int lane = threadIdx.x & 63, wid = threadIdx.x >> 6;
    __syncthreads();
    if (lane == 0) red[wid] = x;
    __syncthreads();
    float s = 0.f;
#pragma unroll
    for (int i = 0; i < NW; i++) s += red[i];
    return s;
}

// ---------------- Gram: G[b] = X_b X_b^T / 1024, row-major bf16 ----------------
__global__ __launch_bounds__(256) void gram_kernel(const float* __restrict__ x,
                                                   u16* __restrict__ Gp) {
    __shared__ __align__(16) u16 Ai[128][72];
    __shared__ __align__(16) u16 Bj[128][72];
    const int b = blockIdx.y;
    const int i0 = (blockIdx.x >> 2) * 128;
    const int j0 = (blockIdx.x & 3) * 128;
    const int t = threadIdx.x;
    const int lane = t & 63, wid = t >> 6;
    const int wm = (wid >> 1) * 64, wn = (wid & 1) * 64;
    f32x4 acc[4][4] = {};
    const float* xb = x + (size_t)b * NC_ * HW;

    for (int kc = 0; kc < HW; kc += 64) {
#pragma unroll
        for (int i = 0; i < 8; i++) {
            int idx = t + 256 * i;  // 128 rows x 16 float4
            int r = idx >> 4, c4 = (idx & 15) * 4;
            float4 qa = *(const float4*)(xb + (size_t)(i0 + r) * HW + kc + c4);
            float4 qb = *(const float4*)(xb + (size_t)(j0 + r) * HW + kc + c4);
            Ai[r][c4 + 0] = f2b(qa.x); Ai[r][c4 + 1] = f2b(qa.y);
            Ai[r][c4 + 2] = f2b(qa.z); Ai[r][c4 + 3] = f2b(qa.w);
            Bj[r][c4 + 0] = f2b(qb.x); Bj[r][c4 + 1] = f2b(qb.y);
            Bj[r][c4 + 2] = f2b(qb.z); Bj[r][c4 + 3] = f2b(qb.w);
        }
        __syncthreads();
#pragma unroll
        for (int ks = 0; ks < 64; ks += 32) {
            const int kk = ks + (lane >> 4) * 8;
            short8 af[4], bf[4];
#pragma unroll
            for (int m = 0; m < 4; m++) af[m] = *(const short8*)&Ai[wm + m * 16 + (lane & 15)][kk];
#pragma unroll
            for (int n = 0; n < 4; n++) bf[n] = *(const short8*)&Bj[wn + n * 16 + (lane & 15)][kk];
#pragma unroll
            for (int m = 0; m < 4; m++)
#pragma unroll
                for (int n = 0; n < 4; n++)
                    acc[m][n] = __builtin_amdgcn_mfma_f32_16x16x32_bf16(af[m], bf[n], acc[m][n], 0, 0, 0);
        }
        __syncthreads();
    }
    const float scale = 1.0f / 1024.0f;
    u16* Gb = Gp + (size_t)b * NC_ * NC_;
#pragma unroll
    for (int m = 0; m < 4; m++) {
#pragma unroll
        for (int n = 0; n < 4; n++) {
            int row = i0 + wm + m * 16 + (lane >> 4) * 4;
            int col = j0 + wn + n * 16 + (lane & 15);
#pragma unroll
            for (int r = 0; r < 4; r++)
                Gb[(size_t)(row + r) * NC_ + col] = f2b(acc[m][n][r] * scale);
        }
    }
}

// ---------------- channel sums ----------------
__global__ __launch_bounds__(256) void colsum_kernel(const float* __restrict__ x,
                                                     float* __restrict__ cs) {
    const int row = blockIdx.x * 4 + (threadIdx.x >> 6);
    const int lane = threadIdx.x & 63;
    const float* p = x + (size_t)row * HW;
    float s = 0.f;
    for (int i = lane; i < HW; i += 64) s += p[i];
#pragma unroll
    for (int m = 32; m >= 1; m >>= 1) s += __shfl_xor(s, m);
    if (lane == 0) cs[row] = s;
}

// ---------------- Lanczos (m=128) + Sturm bisection ----------------
// R5: barrier-minimal schedule (6 syncs/iter on the DGKS skip path, was 7).
//  * alpha partial computed IN the matvec phase from registers, using a
//    transposed v copy v2[(el&7)*64+el>>3] for conflict-free b32 reads
//    (R3's b128 v[lane*8] read was a 16-way conflict; this is the fix that
//    keeps the fusion). Shuffled into red[] before S1 -> no dedicated
//    alpha-reduce barrier.
//  * nb0 (pre-reorth ||w||^2) piggybacks the w-publish barrier; per-pass norm
//    piggybacks the sub2 barrier. DGKS guard scale proxy: alpha^2+beta^2.
//  * matvec: v broadcast reads as 8xb128 into registers; float2 accumulators
//    to invite v_pk_fma_f32.
__global__ __launch_bounds__(1024, 4) void lanczos_kernel(const u16* __restrict__ Gp,
                                                          float* __restrict__ V,
                                                          float* __restrict__ svd_raw) {
    __shared__ __align__(16) float Vl[NV][512];             // 114688 B
    __shared__ __align__(16) float v[512], w[512], v2[512]; // 6144 B
    __shared__ float wpart[16][8][68];                      // 34816 B
    __shared__ float sub2[2][512];                          // 4096 B
    __shared__ float red[16], red2[16];
    __shared__ float al[MLAN], be[MLAN + 1], cc[MLAN];
    const int b = blockIdx.x;
    const int t = threadIdx.x;
    const int lane = t & 63, wid = t >> 6;
    const int el = t & 511, half = t >> 9;
    const int e8 = el & 7, l8 = el >> 3;
    const u16* Gb = Gp + (size_t)b * NC_ * NC_;
    const u16* gp = Gb + (size_t)(wid * 32) * NC_ + lane * 8;  // this thread's slab
    float* Vb = V + (size_t)b * MLAN * 512;

    u32 h = (u32)el * 2654435761u ^ ((u32)b * 0x9E3779B9u);
    h ^= h >> 16; h *= 0x85EBCA6Bu; h ^= h >> 13; h *= 0xC2B2AE35u; h ^= h >> 16;
    float vt = (float)(h & 0xFFFFFFu) * (1.0f / 16777216.0f) - 0.5f;
    float nrm = block_reduce_sum<16>(half == 0 ? vt * vt : 0.f, red);
    vt *= rsqrtf(nrm);
    if (half == 0) {
        v[el] = vt;
        v2[e8 * 64 + l8] = vt;
        Vl[0][el] = vt;
    }
    float vprev = 0.f, beta = 0.f;
    __syncthreads();

    for (int j = 0; j < MLAN; j++) {
        // ---- matvec: coalesced 16B loads over this wave's 32-row slab ----
        f32x2 q01 = {0.f, 0.f}, q23 = {0.f, 0.f}, q45 = {0.f, 0.f}, q67 = {0.f, 0.f};
        // broadcast-load this wave's 32 v entries into registers (8 x b128)
        float vkr[32];
#pragma unroll
        for (int c = 0; c < 8; c++) *(float4*)&vkr[c * 4] = *(const float4*)&v[wid * 32 + c * 4];
#pragma unroll 16
        for (int kk = 0; kk < 32; kk++) {
            short8 g = *(const short8*)(gp + (size_t)kk * NC_);
            const u32* gu = (const u32*)&g;
            float vv = vkr[kk];
            f32x2 vv2 = {vv, vv};
            u32 u0 = gu[0], u1 = gu[1], u2 = gu[2], u3 = gu[3];
            f32x2 f01 = {__uint_as_float(u0 << 16), __uint_as_float(u0 & 0xFFFF0000u)};
            f32x2 f23 = {__uint_as_float(u1 << 16), __uint_as_float(u1 & 0xFFFF0000u)};
            f32x2 f45 = {__uint_as_float(u2 << 16), __uint_as_float(u2 & 0xFFFF0000u)};
            f32x2 f67 = {__uint_as_float(u3 << 16), __uint_as_float(u3 & 0xFFFF0000u)};
            q01 += f01 * vv2;
            q23 += f23 * vv2;
            q45 += f45 * vv2;
            q67 += f67 * vv2;
        }
        // column c = lane*8+e owned by this thread -> wpart[wid][e][lane]
        wpart[wid][0][lane] = q01.x; wpart[wid][1][lane] = q01.y;
        wpart[wid][2][lane] = q23.x; wpart[wid][3][lane] = q23.y;
        wpart[wid][4][lane] = q45.x; wpart[wid][5][lane] = q45.y;
        wpart[wid][6][lane] = q67.x; wpart[wid][7][lane] = q67.y;
        // fused alpha partial via transposed v2 (conflict-free b32 reads)
        float ap = q01.x * v2[lane] + q01.y * v2[64 + lane]
                 + q23.x * v2[128 + lane] + q23.y * v2[192 + lane]
                 + q45.x * v2[256 + lane] + q45.y * v2[320 + lane]
                 + q67.x * v2[384 + lane] + q67.y * v2[448 + lane];
#pragma unroll
        for (int m = 32; m >= 1; m >>= 1) ap += __shfl_xor(ap, m);
        if (lane == 0) red[wid] = ap;
        __syncthreads();  // S1: wpart + alpha partials

        float acc = 0.f;
#pragma unroll
        for (int p = 0; p < 16; p++) acc += wpart[p][e8][l8];
        float alpha = 0.f;
#pragma unroll
        for (int i = 0; i < 16; i++) alpha += red[i];
        float wt = acc - alpha * vt - beta * vprev;
        if (half == 0) w[el] = wt;
        // nb0 partial (half0 waves cover all 512 elements exactly once)
        float pz = wt * wt;
#pragma unroll
        for (int m = 32; m >= 1; m >>= 1) pz += __shfl_xor(pz, m);
        if (lane == 0 && wid < 8) red2[wid] = pz;
        __syncthreads();  // S2: w + nb0 partials
        float nb0 = 0.f;
#pragma unroll
        for (int i = 0; i < 8; i++) nb0 += red2[i];
        const float gscale = nb0 + alpha * alpha + beta * beta;

        float nb = 0.f;
        for (int pass = 0;; pass++) {
            // ---- dots cc[i] = <V_i, w> ----
            const float4 wv0 = *(const float4*)&w[lane * 4];
            const float4 wv1 = *(const float4*)&w[256 + lane * 4];
            for (int i = wid; i <= j; i += 16) {
                float4 x0, x1;
                if (i < NV) {
                    x0 = *(const float4*)&Vl[i][lane * 4];
                    x1 = *(const float4*)&Vl[i][256 + lane * 4];
                } else {
                    const float* Vi = Vb + (size_t)i * 512;
                    x0 = *(const float4*)(Vi + lane * 4);
                    x1 = *(const float4*)(Vi + 256 + lane * 4);
                }
                float p = x0.x * wv0.x + x0.y * wv0.y + x0.z * wv0.z + x0.w * wv0.w
                        + x1.x * wv1.x + x1.y * wv1.y + x1.z * wv1.z + x1.w * wv1.w;
#pragma unroll
                for (int m = 32; m >= 1; m >>= 1) p += __shfl_xor(p, m);
                if (lane == 0) cc[i] = p;
            }
            __syncthreads();  // S3: cc published
            // ---- subtract: halves split the i-range; combine via sub2 ----
            const int n = j + 1, ns = n >> 1;
            const int ib = half ? ns : 0, ie = half ? n : ns;
            float sub = 0.f;
            int i = ib;
            const int iLe = (ie < NV) ? ie : NV;
            for (; i + 4 <= iLe; i += 4)
                sub += cc[i + 0] * Vl[i + 0][el] + cc[i + 1] * Vl[i + 1][el]
                     + cc[i + 2] * Vl[i + 2][el] + cc[i + 3] * Vl[i + 3][el];
            for (; i < iLe; i++) sub += cc[i] * Vl[i][el];
            if (i < ib) i = ib;
            for (; i + 4 <= ie; i += 4)
                sub += cc[i + 0] * Vb[(size_t)(i + 0) * 512 + el]
                     + cc[i + 1] * Vb[(size_t)(i + 1) * 512 + el]
                     + cc[i + 2] * Vb[(size_t)(i + 2) * 512 + el]
                     + cc[i + 3] * Vb[(size_t)(i + 3) * 512 + el];
            for (; i < ie; i++) sub += cc[i] * Vb[(size_t)i * 512 + el];
            sub2[half][el] = sub;
            __syncthreads();  // S4: sub2 published
            wt = wt - sub2[0][el] - sub2[1][el];
            if (half == 0) w[el] = wt;  // republish for (rare) pass 2
            float pn = wt * wt;
#pragma unroll
            for (int m = 32; m >= 1; m >>= 1) pn += __shfl_xor(pn, m);
            if (lane == 0 && wid < 8) red[wid] = pn;
            __syncthreads();  // S5: norm partials + w
            nb = 0.f;
#pragma unroll
            for (int q = 0; q < 8; q++) nb += red[q];
            // DGKS "twice is enough": skip pass 2 when pass 1 kept the norm,
            // absolute guard forces pass 2 on heavy cancellation.
            if (pass == 1 || (nb > 0.5f * nb0 && nb0 > 1e-8f * gscale)) break;
            nb0 = nb;
        }
        float betn = sqrtf(nb);
        bool ok = (betn > 1e-20f) && (betn == betn) && !isinf(betn);
        if (t == 0) { al[j] = alpha; be[j + 1] = ok ? betn : 0.f; }
        float inv = ok ? 1.0f / betn : 0.f;
        vprev = vt;
        vt = ok ? wt * inv : 0.f;
        if (half == 0) {
            v[el] = vt;
            v2[e8 * 64 + l8] = vt;
            if (j + 1 < NV) Vl[j + 1][el] = vt;
            else if (j + 1 < MLAN) Vb[(size_t)(j + 1) * 512 + el] = vt;
        }
        beta = ok ? betn : 0.f;
        __syncthreads();  // S6: v published
    }

    if (t < NR) {
        float lo = 1e30f, hi = -1e30f;
        for (int i = 0; i < MLAN; i++) {
            float bl = (i > 0) ? fabsf(be[i]) : 0.f;
            float br = (i + 1 < MLAN) ? fabsf(be[i + 1]) : 0.f;
            lo = fminf(lo, al[i] - bl - br);
            hi = fmaxf(hi, al[i] + bl + br);
        }
        const int i0 = MLAN - 1 - t;
        for (int it = 0; it < 30; it++) {
            float mid = 0.5f * (lo + hi);
            int cnt = 0;
            float d = 1.0f;
            for (int i = 0; i < MLAN; i++) {
                float bb2 = (i > 0) ? be[i] * be[i] : 0.f;
                float dp = d;
                if (fabsf(dp) < 1e-30f) dp = (dp < 0.f) ? -1e-30f : 1e-30f;
                d = (al[i] - mid) - bb2 / dp;
                cnt += (d < 0.f);
            }
            if (cnt > i0) hi = mid; else lo = mid;
        }
        float ev = fmaxf(0.5f * (lo + hi), 0.f);
        float val = log1pf(sqrtf(ev));
        if (!(val == val) || isinf(val)) val = 1.0f;
        svd_raw[b * NR + t] = val;
    }
}

// ---------------- emb -> cos -> top3 -> gate ----------------
__global__ __launch_bounds__(256) void embgate_kernel(
    const float* __restrict__ cs, const float* __restrict__ W_emb,
    const float* __restrict__ g_emb, const float* __restrict__ beta_emb,
    const float* __restrict__ anchors, float* __restrict__ tg_out) {
    const int b = blockIdx.x, t = threadIdx.x;
    __shared__ float csl[512], embv[256], cosv[32], tgs[32];
    __shared__ float red[4];

    for (int i = t; i < 512; i += 256) csl[i] = cs[b * 512 + i];
    __syncthreads();

    float e = 0.f;
    for (int c = 0; c < 512; c++) e += csl[c] * W_emb[c * NE + t];
    e *= (1.0f / 1024.0f);
    float mean = block_reduce_sum<4>(e, red) * (1.0f / 256.0f);
    float dv = e - mean;
    float var = block_reduce_sum<4>(dv * dv, red) * (1.0f / 256.0f);
    e = dv * rsqrtf(var + 1e-5f) * g_emb[t] + beta_emb[t];
    float nn = block_reduce_sum<4>(e * e, red);
    e = e / fmaxf(sqrtf(nn), 1e-12f);
    embv[t] = e;
    __syncthreads();

    if (t < 32) {
        float p = 0.f, na = 0.f;
        for (int q = 0; q < 256; q++) {
            float av = anchors[t * NE + q];
            p += embv[q] * av;
            na += av * av;
        }
        cosv[t] = p / fmaxf(sqrtf(na), 1e-12f);
    }
    __syncthreads();

    if (t == 0) {
        int i1 = 0, i2 = 0, i3 = 0;
        float v1 = -1e30f, v2 = -1e30f, v3 = -1e30f;
        for (int a = 0; a < 32; a++) {
            float cv = cosv[a];
            if (cv > v1) { v3 = v2; i3 = i2; v2 = v1; i2 = i1; v1 = cv; i1 = a; }
            else if (cv > v2) { v3 = v2; i3 = i2; v2 = cv; i2 = a; }
            else if (cv > v3) { v3 = cv; i3 = a; }
        }
        float e2 = expf(v2 - v1), e3 = expf(v3 - v1);
        float ss = 1.0f + e2 + e3;
        for (int a = 0; a < 32; a++) tgs[a] = 0.f;
        tgs[i1] = (1.0f - v1) * 1.0f / ss;
        tgs[i2] = (1.0f - v2) * e2 / ss;
        tgs[i3] = (1.0f - v3) * e3 / ss;
    }
    __syncthreads();
    if (t < 32) tg_out[b * 32 + t] = tgs[t];
}

// ---------------- compartment MLPs -> pw ----------------
__global__ __launch_bounds__(256) void mlp_kernel(
    const float* __restrict__ tg, const float* __restrict__ Wc1,
    const float* __restrict__ bc1, const float* __restrict__ Wc2,
    const float* __restrict__ bc2, const float* __restrict__ g_c,
    const float* __restrict__ beta_c, float* __restrict__ pw_out) {
    const int b = blockIdx.x, t = threadIdx.x;
    __shared__ float tgl[32], hbuf[512], pcb[256];

    if (t < 32) tgl[t] = tg[b * 32 + t];
    __syncthreads();

    for (int o = t; o < 512; o += 256) {
        int c = o >> 6, d = o & 63;
        float s = bc1[c * 64 + d];
        for (int a = 0; a < 32; a++) s += tgl[a] * Wc1[(c * 32 + a) * 64 + d];
        hbuf[o] = gelu_exact(s);
    }
    __syncthreads();

    const int c = t >> 5, e = t & 31;
    float s = bc2[c * 32 + e];
    for (int d = 0; d < 64; d++) s += hbuf[c * 64 + d] * Wc2[(c * 64 + d) * 32 + e];
    pcb[t] = s;
    __syncthreads();

    float mean = 0.f;
    for (int k = 0; k < 32; k++) mean += pcb[c * 32 + k];
    mean *= (1.0f / 32.0f);
    float var = 0.f;
    for (int k = 0; k < 32; k++) { float dd = pcb[c * 32 + k] - mean; var += dd * dd; }
    var *= (1.0f / 32.0f);
    pw_out[b * PW_ + t] = (s - mean) * rsqrtf(var + 1e-5f) * g_c[c * 32 + e] + beta_c[c * 32 + e];
}

// ---------------- svd_ctx ----------------
__global__ __launch_bounds__(256) void ctx_kernel(
    const float* __restrict__ svd_raw, const float* __restrict__ W_svd,
    const float* __restrict__ b_svd, const float* __restrict__ g_svd,
    const float* __restrict__ beta_svd, float* __restrict__ ctx_out) {
    const int b = blockIdx.x, t = threadIdx.x;
    __shared__ float rawv[NR];
    __shared__ float red[4];
    if (t < NR) rawv[t] = svd_raw[b * NR + t];
    __syncthreads();
    float sv = b_svd[t];
    for (int r = 0; r < NR; r++) sv += rawv[r] * W_svd[r * PW_ + t];
    float mean = block_reduce_sum<4>(sv, red) * (1.0f / 256.0f);
    float dv = sv - mean;
    float var = block_reduce_sum<4>(dv * dv, red) * (1.0f / 256.0f);
    ctx_out[b * PW_ + t] = gelu_exact(dv * rsqrtf(var + 1e-5f) * g_svd[t] + beta_svd[t]);
}

// ---------------- cw + geo_out (f32) ----------------
__global__ __launch_bounds__(256) void cwgeo_kernel(
    const float* __restrict__ pw, const float* __restrict__ ctx,
    const float* __restrict__ geo_state, const float* __restrict__ W_mod,
    const float* __restrict__ b_mod, const float* __restrict__ geo_gate,
    const float* __restrict__ W_geo, const float* __restrict__ b_geo,
    const float* __restrict__ g_geo, const float* __restrict__ beta_geo,
    float* __restrict__ cw, float* __restrict__ out_geo) {
    const int b = blockIdx.x, t = threadIdx.x;
    __shared__ float mi[768];
    __shared__ float red[4];
    mi[t] = pw[b * PW_ + t];
    mi[256 + t] = ctx[b * PW_ + t];
    float geo = geo_state[b * PW_ + t];
    mi[512 + t] = geo;
    __syncthreads();

    float gg = b_geo[t];
    for (int q = 0; q < PW_; q++) gg += mi[q] * W_geo[q * PW_ + t];
    float gmean = block_reduce_sum<4>(gg, red) * (1.0f / 256.0f);
    float gdv = gg - gmean;
    float gvar = block_reduce_sum<4>(gdv * gdv, red) * (1.0f / 256.0f);
    float lnv = gdv * rsqrtf(gvar + 1e-5f) * g_geo[t] + beta_geo[t];
    out_geo[b * PW_ + t] = geo + sigmoidf_(geo_gate[t]) * lnv;

    for (int c = t; c < 512; c += 256) {
        float s = b_mod[c];
        for (int k = 0; k < 768; k++) s += mi[k] * W_mod[k * NC_ + c];
        cw[b * NC_ + c] = sigmoidf_(s);
    }
}

// ---------------- x_out(f32) = x(f32) * cw[b,c] ----------------
__global__ __launch_bounds__(256) void modulate_kernel(const float* __restrict__ x,
                                                       const float* __restrict__ cw,
                                                       float* __restrict__ out) {
    const int i4 = blockIdx.x * 256 + threadIdx.x;  // float4 index
    const float4* xp = (const float4*)x;
    float4 q = xp[i4];
    const float wv = cw[i4 >> 8];  // (i4*4)>>10 = b*512+c
    float4 o;
    o.x = q.x * wv; o.y = q.y * wv; o.z = q.z * wv; o.w = q.w * wv;
    ((float4*)out)[i4] = o;
}

extern "C" void kernel_launch(void* const* d_in, const int* in_sizes, int n_in,
                              void* d_out, int out_size, void* d_ws, size_t ws_size,
                              hipStream_t stream) {
    const float* x = (const float*)d_in[0];
    const float* geo_state = (const float*)d_in[1];
    const float* W_svd = (const float*)d_in[2];
    const float* b_svd = (const float*)d_in[3];
    const float* g_svd = (const float*)d_in[4];
    const float* beta_svd = (const float*)d_in[5];
    const float* W_emb = (const float*)d_in[6];
    const float* g_emb = (const float*)d_in[7];
    const float* beta_emb = (const float*)d_in[8];
    const float* anchors = (const float*)d_in[9];
    const float* Wc1 = (const float*)d_in[10];
    const float* bc1 = (const float*)d_in[11];
    const float* Wc2 = (const float*)d_in[12];
    const float* bc2 = (const float*)d_in[13];
    const float* g_c = (const float*)d_in[14];
    const float* beta_c = (const float*)d_in[15];
    const float* W_mod = (const float*)d_in[16];
    const float* b_mod = (const float*)d_in[17];
    const float* geo_gate = (const float*)d_in[18];
    const float* W_geo = (const float*)d_in[19];
    const float* b_geo = (const float*)d_in[20];
    const float* g_geo = (const float*)d_in[21];
    const float* beta_geo = (const float*)d_in[22];

    // d_out is FLOAT32: x_out = 16,777,216 f32 (67,108,864 B) + geo_out 8192 f32.
    // Scratch staged in d_out's first 28 MB; fully consumed before modulate
    // overwrites [0, 67,108,864) (stream-ordered). cw lives in d_ws.
    char* ob = (char*)d_out;
    u16* G = (u16*)(ob);                      // 16,777,216 B
    float* V = (float*)(ob + 16777216);       //  8,388,608 B -> 25,165,824
    float* cs = (float*)(ob + 25165824);      //     65,536 B -> 25,231,360
    float* svdraw = (float*)(ob + 25231360);  //      3,072 B -> 25,234,432
    float* tg = (float*)(ob + 25234432);      //      4,096 B -> 25,238,528
    float* pw = (float*)(ob + 25238528);      //     32,768 B -> 25,271,296
    float* ctxb = (float*)(ob + 25271296);    //     32,768 B -> 25,304,064
    float* cw = (float*)d_ws;                 //     65,536 B

    float* outx = (float*)d_out;
    float* outg = outx + 16777216;

    gram_kernel<<<dim3(16, 32), dim3(256), 0, stream>>>(x, G);
    colsum_kernel<<<dim3(4096), dim3(256), 0, stream>>>(x, cs);
    lanczos_kernel<<<dim3(32), dim3(1024), 0, stream>>>(G, V, svdraw);
    embgate_kernel<<<dim3(32), dim3(256), 0, stream>>>(cs, W_emb, g_emb, beta_emb, anchors, tg);
    mlp_kernel<<<dim3(32), dim3(256), 0, stream>>>(tg, Wc1, bc1, Wc2, bc2, g_c, beta_c, pw);
    ctx_kernel<<<dim3(32), dim3(256), 0, stream>>>(svdraw, W_svd, b_svd, g_svd, beta_svd, ctxb);
    cwgeo_kernel<<<dim3(32), dim3(256), 0, stream>>>(pw, ctxb, geo_state, W_mod, b_mod,
                                                     geo_gate, W_geo, b_geo, g_geo, beta_geo,
                                                     cw, outg);
    modulate_kernel<<<dim3(16384), dim3(256), 0, stream>>>(x, cw, outx);
}

// Round 6
// 1846.553 us; speedup vs baseline: 1.4991x; 1.4991x over previous
//
#include <hip/hip_runtime.h>
#include <hip/hip_bf16.h>

typedef unsigned short u16;
typedef unsigned int u32;
typedef __attribute__((ext_vector_type(8))) short short8;
typedef __attribute__((ext_vector_type(4))) float f32x4;

#define NB 32
#define NC_ 512
#define HW 1024
#define NE 256
#define NA 32
#define NR 24
#define PW_ 256
#define MLAN 128
#define NV 56  // Lanczos vectors cached in LDS (f32)

__device__ inline float b2f(u16 u) { return __uint_as_float(((u32)u) << 16); }
__device__ inline u16 f2b(float f) {
    u32 x = __float_as_uint(f);
    u32 r = x + 0x7FFFu + ((x >> 16) & 1u);
    return (u16)(r >> 16);
}
__device__ inline float gelu_exact(float x) {
    return 0.5f * x * (1.0f + erff(x * 0.70710678118654752f));
}
__device__ inline float sigmoidf_(float x) { return 1.0f / (1.0f + expf(-x)); }

template <int NW>
__device__ inline float block_reduce_sum(float x, volatile float* red) {
#pragma unroll
    for (int m = 32; m >= 1; m >>= 1) x += __shfl_xor(x, m);
    const int lane = threadIdx.x & 63, wid = threadIdx.x >> 6;
    __syncthreads();
    if (lane == 0) red[wid] = x;
    __syncthreads();
    float s = 0.f;
#pragma unroll
    for (int i = 0; i < NW; i++) s += red[i];
    return s;
}

// ---------------- Gram: G[b] = X_b X_b^T / 1024, row-major bf16 ----------------
__global__ __launch_bounds__(256) void gram_kernel(const float* __restrict__ x,
                                                   u16* __restrict__ Gp) {
    __shared__ __align__(16) u16 Ai[128][72];
    __shared__ __align__(16) u16 Bj[128][72];
    const int b = blockIdx.y;
    const int i0 = (blockIdx.x >> 2) * 128;
    const int j0 = (blockIdx.x & 3) * 128;
    const int t = threadIdx.x;
    const int lane = t & 63, wid = t >> 6;
    const int wm = (wid >> 1) * 64, wn = (wid & 1) * 64;
    f32x4 acc[4][4] = {};
    const float* xb = x + (size_t)b * NC_ * HW;

    for (int kc = 0; kc < HW; kc += 64) {
#pragma unroll
        for (int i = 0; i < 8; i++) {
            int idx = t + 256 * i;  // 128 rows x 16 float4
            int r = idx >> 4, c4 = (idx & 15) * 4;
            float4 qa = *(const float4*)(xb + (size_t)(i0 + r) * HW + kc + c4);
            float4 qb = *(const float4*)(xb + (size_t)(j0 + r) * HW + kc + c4);
            Ai[r][c4 + 0] = f2b(qa.x); Ai[r][c4 + 1] = f2b(qa.y);
            Ai[r][c4 + 2] = f2b(qa.z); Ai[r][c4 + 3] = f2b(qa.w);
            Bj[r][c4 + 0] = f2b(qb.x); Bj[r][c4 + 1] = f2b(qb.y);
            Bj[r][c4 + 2] = f2b(qb.z); Bj[r][c4 + 3] = f2b(qb.w);
        }
        __syncthreads();
#pragma unroll
        for (int ks = 0; ks < 64; ks += 32) {
            const int kk = ks + (lane >> 4) * 8;
            short8 af[4], bf[4];
#pragma unroll
            for (int m = 0; m < 4; m++) af[m] = *(const short8*)&Ai[wm + m * 16 + (lane & 15)][kk];
#pragma unroll
            for (int n = 0; n < 4; n++) bf[n] = *(const short8*)&Bj[wn + n * 16 + (lane & 15)][kk];
#pragma unroll
            for (int m = 0; m < 4; m++)
#pragma unroll
                for (int n = 0; n < 4; n++)
                    acc[m][n] = __builtin_amdgcn_mfma_f32_16x16x32_bf16(af[m], bf[n], acc[m][n], 0, 0, 0);
        }
        __syncthreads();
    }
    const float scale = 1.0f / 1024.0f;
    u16* Gb = Gp + (size_t)b * NC_ * NC_;
#pragma unroll
    for (int m = 0; m < 4; m++) {
#pragma unroll
        for (int n = 0; n < 4; n++) {
            int row = i0 + wm + m * 16 + (lane >> 4) * 4;
            int col = j0 + wn + n * 16 + (lane & 15);
#pragma unroll
            for (int r = 0; r < 4; r++)
                Gb[(size_t)(row + r) * NC_ + col] = f2b(acc[m][n][r] * scale);
        }
    }
}

// ---------------- channel sums ----------------
__global__ __launch_bounds__(256) void colsum_kernel(const float* __restrict__ x,
                                                     float* __restrict__ cs) {
    const int row = blockIdx.x * 4 + (threadIdx.x >> 6);
    const int lane = threadIdx.x & 63;
    const float* p = x + (size_t)row * HW;
    float s = 0.f;
    for (int i = lane; i < HW; i += 64) s += p[i];
#pragma unroll
    for (int m = 32; m >= 1; m >>= 1) s += __shfl_xor(s, m);
    if (lane == 0) cs[row] = s;
}

// ---------------- Lanczos (m=128) + Sturm bisection ----------------
// R6 = R4's proven matvec body (direct LDS v reads, scalar accumulators --
// NO private array, the R5 vkr[] was runtime-indexed -> scratch spill,
// 320MB/dispatch HBM writes) + R5's structural wins kept:
//  * alpha partial fused into matvec phase via transposed v2 copy
//    (stride 66 to de-conflict the write); no dedicated alpha barrier.
//  * nb0 piggybacks the w-publish barrier; per-pass norm piggybacks sub2.
//  * 6 syncs/iter on the DGKS skip path.
__global__ __launch_bounds__(1024, 4) void lanczos_kernel(const u16* __restrict__ Gp,
                                                          float* __restrict__ V,
                                                          float* __restrict__ svd_raw) {
    __shared__ __align__(16) float Vl[NV][512];     // 114688 B
    __shared__ __align__(16) float v[512], w[512];  // 4096 B
    __shared__ float v2[528];                       // 2112 B (stride 66)
    __shared__ float wpart[16][8][68];              // 34816 B
    __shared__ float sub2[2][512];                  // 4096 B
    __shared__ float red[16], red2[16];
    __shared__ float al[MLAN], be[MLAN + 1], cc[MLAN];
    const int b = blockIdx.x;
    const int t = threadIdx.x;
    const int lane = t & 63, wid = t >> 6;
    const int el = t & 511, half = t >> 9;
    const int e8 = el & 7, l8 = el >> 3;
    const u16* Gb = Gp + (size_t)b * NC_ * NC_;
    const u16* gp = Gb + (size_t)(wid * 32) * NC_ + lane * 8;  // this thread's slab
    float* Vb = V + (size_t)b * MLAN * 512;

    u32 h = (u32)el * 2654435761u ^ ((u32)b * 0x9E3779B9u);
    h ^= h >> 16; h *= 0x85EBCA6Bu; h ^= h >> 13; h *= 0xC2B2AE35u; h ^= h >> 16;
    float vt = (float)(h & 0xFFFFFFu) * (1.0f / 16777216.0f) - 0.5f;
    float nrm = block_reduce_sum<16>(half == 0 ? vt * vt : 0.f, red);
    vt *= rsqrtf(nrm);
    if (half == 0) {
        v[el] = vt;
        v2[e8 * 66 + l8] = vt;
        Vl[0][el] = vt;
    }
    float vprev = 0.f, beta = 0.f;
    __syncthreads();

    for (int j = 0; j < MLAN; j++) {
        // ---- matvec partials: coalesced 16B loads over this wave's 32-row slab ----
        float a0 = 0.f, a1 = 0.f, a2 = 0.f, a3 = 0.f;
        float a4 = 0.f, a5 = 0.f, a6 = 0.f, a7 = 0.f;
        const float* vk = v + wid * 32;
#pragma unroll 16
        for (int kk = 0; kk < 32; kk++) {
            short8 g = *(const short8*)(gp + (size_t)kk * NC_);
            float vv = vk[kk];
            a0 += b2f((u16)g[0]) * vv;
            a1 += b2f((u16)g[1]) * vv;
            a2 += b2f((u16)g[2]) * vv;
            a3 += b2f((u16)g[3]) * vv;
            a4 += b2f((u16)g[4]) * vv;
            a5 += b2f((u16)g[5]) * vv;
            a6 += b2f((u16)g[6]) * vv;
            a7 += b2f((u16)g[7]) * vv;
        }
        // column c = lane*8+e owned by this thread -> wpart[wid][e][lane]
        wpart[wid][0][lane] = a0; wpart[wid][1][lane] = a1;
        wpart[wid][2][lane] = a2; wpart[wid][3][lane] = a3;
        wpart[wid][4][lane] = a4; wpart[wid][5][lane] = a5;
        wpart[wid][6][lane] = a6; wpart[wid][7][lane] = a7;
        // fused alpha partial: v2[e*66+lane] = v[lane*8+e], stride-1 reads
        float ap = a0 * v2[lane] + a1 * v2[66 + lane]
                 + a2 * v2[132 + lane] + a3 * v2[198 + lane]
                 + a4 * v2[264 + lane] + a5 * v2[330 + lane]
                 + a6 * v2[396 + lane] + a7 * v2[462 + lane];
#pragma unroll
        for (int m = 32; m >= 1; m >>= 1) ap += __shfl_xor(ap, m);
        if (lane == 0) red[wid] = ap;
        __syncthreads();  // S1: wpart + alpha partials

        float acc = 0.f;
#pragma unroll
        for (int p = 0; p < 16; p++) acc += wpart[p][e8][l8];
        float alpha = 0.f;
#pragma unroll
        for (int i = 0; i < 16; i++) alpha += red[i];
        float wt = acc - alpha * vt - beta * vprev;
        if (half == 0) w[el] = wt;
        // nb0 partial (half0 waves cover all 512 elements exactly once)
        float pz = wt * wt;
#pragma unroll
        for (int m = 32; m >= 1; m >>= 1) pz += __shfl_xor(pz, m);
        if (lane == 0 && wid < 8) red2[wid] = pz;
        __syncthreads();  // S2: w + nb0 partials
        float nb0 = 0.f;
#pragma unroll
        for (int i = 0; i < 8; i++) nb0 += red2[i];
        const float gscale = nb0 + alpha * alpha + beta * beta;

        float nb = 0.f;
        for (int pass = 0;; pass++) {
            // ---- dots cc[i] = <V_i, w> ----
            const float4 wv0 = *(const float4*)&w[lane * 4];
            const float4 wv1 = *(const float4*)&w[256 + lane * 4];
            for (int i = wid; i <= j; i += 16) {
                float4 x0, x1;
                if (i < NV) {
                    x0 = *(const float4*)&Vl[i][lane * 4];
                    x1 = *(const float4*)&Vl[i][256 + lane * 4];
                } else {
                    const float* Vi = Vb + (size_t)i * 512;
                    x0 = *(const float4*)(Vi + lane * 4);
                    x1 = *(const float4*)(Vi + 256 + lane * 4);
                }
                float p = x0.x * wv0.x + x0.y * wv0.y + x0.z * wv0.z + x0.w * wv0.w
                        + x1.x * wv1.x + x1.y * wv1.y + x1.z * wv1.z + x1.w * wv1.w;
#pragma unroll
                for (int m = 32; m >= 1; m >>= 1) p += __shfl_xor(p, m);
                if (lane == 0) cc[i] = p;
            }
            __syncthreads();  // S3: cc published
            // ---- subtract: halves split the i-range; combine via sub2 ----
            const int n = j + 1, ns = n >> 1;
            const int ib = half ? ns : 0, ie = half ? n : ns;
            float sub = 0.f;
            int i = ib;
            const int iLe = (ie < NV) ? ie : NV;
            for (; i + 4 <= iLe; i += 4)
                sub += cc[i + 0] * Vl[i + 0][el] + cc[i + 1] * Vl[i + 1][el]
                     + cc[i + 2] * Vl[i + 2][el] + cc[i + 3] * Vl[i + 3][el];
            for (; i < iLe; i++) sub += cc[i] * Vl[i][el];
            if (i < ib) i = ib;
            for (; i + 4 <= ie; i += 4)
                sub += cc[i + 0] * Vb[(size_t)(i + 0) * 512 + el]
                     + cc[i + 1] * Vb[(size_t)(i + 1) * 512 + el]
                     + cc[i + 2] * Vb[(size_t)(i + 2) * 512 + el]
                     + cc[i + 3] * Vb[(size_t)(i + 3) * 512 + el];
            for (; i < ie; i++) sub += cc[i] * Vb[(size_t)i * 512 + el];
            sub2[half][el] = sub;
            __syncthreads();  // S4: sub2 published
            wt = wt - sub2[0][el] - sub2[1][el];
            if (half == 0) w[el] = wt;  // republish for (rare) pass 2
            float pn = wt * wt;
#pragma unroll
            for (int m = 32; m >= 1; m >>= 1) pn += __shfl_xor(pn, m);
            if (lane == 0 && wid < 8) red[wid] = pn;
            __syncthreads();  // S5: norm partials + w
            nb = 0.f;
#pragma unroll
            for (int q = 0; q < 8; q++) nb += red[q];
            // DGKS "twice is enough": skip pass 2 when pass 1 kept the norm,
            // absolute guard forces pass 2 on heavy cancellation.
            if (pass == 1 || (nb > 0.5f * nb0 && nb0 > 1e-8f * gscale)) break;
            nb0 = nb;
        }
        float betn = sqrtf(nb);
        bool ok = (betn > 1e-20f) && (betn == betn) && !isinf(betn);
        if (t == 0) { al[j] = alpha; be[j + 1] = ok ? betn : 0.f; }
        float inv = ok ? 1.0f / betn : 0.f;
        vprev = vt;
        vt = ok ? wt * inv : 0.f;
        if (half == 0) {
            v[el] = vt;
            v2[e8 * 66 + l8] = vt;
            if (j + 1 < NV) Vl[j + 1][el] = vt;
            else if (j + 1 < MLAN) Vb[(size_t)(j + 1) * 512 + el] = vt;
        }
        beta = ok ? betn : 0.f;
        __syncthreads();  // S6: v published
    }

    if (t < NR) {
        float lo = 1e30f, hi = -1e30f;
        for (int i = 0; i < MLAN; i++) {
            float bl = (i > 0) ? fabsf(be[i]) : 0.f;
            float br = (i + 1 < MLAN) ? fabsf(be[i + 1]) : 0.f;
            lo = fminf(lo, al[i] - bl - br);
            hi = fmaxf(hi, al[i] + bl + br);
        }
        const int i0 = MLAN - 1 - t;
        for (int it = 0; it < 30; it++) {
            float mid = 0.5f * (lo + hi);
            int cnt = 0;
            float d = 1.0f;
            for (int i = 0; i < MLAN; i++) {
                float bb2 = (i > 0) ? be[i] * be[i] : 0.f;
                float dp = d;
                if (fabsf(dp) < 1e-30f) dp = (dp < 0.f) ? -1e-30f : 1e-30f;
                d = (al[i] - mid) - bb2 / dp;
                cnt += (d < 0.f);
            }
            if (cnt > i0) hi = mid; else lo = mid;
        }
        float ev = fmaxf(0.5f * (lo + hi), 0.f);
        float val = log1pf(sqrtf(ev));
        if (!(val == val) || isinf(val)) val = 1.0f;
        svd_raw[b * NR + t] = val;
    }
}

// ---------------- emb -> cos -> top3 -> gate ----------------
__global__ __launch_bounds__(256) void embgate_kernel(
    const float* __restrict__ cs, const float* __restrict__ W_emb,
    const float* __restrict__ g_emb, const float* __restrict__ beta_emb,
    const float* __restrict__ anchors, float* __restrict__ tg_out) {
    const int b = blockIdx.x, t = threadIdx.x;
    __shared__ float csl[512], embv[256], cosv[32], tgs[32];
    __shared__ float red[4];

    for (int i = t; i < 512; i += 256) csl[i] = cs[b * 512 + i];
    __syncthreads();

    float e = 0.f;
    for (int c = 0; c < 512; c++) e += csl[c] * W_emb[c * NE + t];
    e *= (1.0f / 1024.0f);
    float mean = block_reduce_sum<4>(e, red) * (1.0f / 256.0f);
    float dv = e - mean;
    float var = block_reduce_sum<4>(dv * dv, red) * (1.0f / 256.0f);
    e = dv * rsqrtf(var + 1e-5f) * g_emb[t] + beta_emb[t];
    float nn = block_reduce_sum<4>(e * e, red);
    e = e / fmaxf(sqrtf(nn), 1e-12f);
    embv[t] = e;
    __syncthreads();

    if (t < 32) {
        float p = 0.f, na = 0.f;
        for (int q = 0; q < 256; q++) {
            float av = anchors[t * NE + q];
            p += embv[q] * av;
            na += av * av;
        }
        cosv[t] = p / fmaxf(sqrtf(na), 1e-12f);
    }
    __syncthreads();

    if (t == 0) {
        int i1 = 0, i2 = 0, i3 = 0;
        float v1 = -1e30f, v2 = -1e30f, v3 = -1e30f;
        for (int a = 0; a < 32; a++) {
            float cv = cosv[a];
            if (cv > v1) { v3 = v2; i3 = i2; v2 = v1; i2 = i1; v1 = cv; i1 = a; }
            else if (cv > v2) { v3 = v2; i3 = i2; v2 = cv; i2 = a; }
            else if (cv > v3) { v3 = cv; i3 = a; }
        }
        float e2 = expf(v2 - v1), e3 = expf(v3 - v1);
        float ss = 1.0f + e2 + e3;
        for (int a = 0; a < 32; a++) tgs[a] = 0.f;
        tgs[i1] = (1.0f - v1) * 1.0f / ss;
        tgs[i2] = (1.0f - v2) * e2 / ss;
        tgs[i3] = (1.0f - v3) * e3 / ss;
    }
    __syncthreads();
    if (t < 32) tg_out[b * 32 + t] = tgs[t];
}

// ---------------- compartment MLPs -> pw ----------------
__global__ __launch_bounds__(256) void mlp_kernel(
    const float* __restrict__ tg, const float* __restrict__ Wc1,
    const float* __restrict__ bc1, const float* __restrict__ Wc2,
    const float* __restrict__ bc2, const float* __restrict__ g_c,
    const float* __restrict__ beta_c, float* __restrict__ pw_out) {
    const int b = blockIdx.x, t = threadIdx.x;
    __shared__ float tgl[32], hbuf[512], pcb[256];

    if (t < 32) tgl[t] = tg[b * 32 + t];
    __syncthreads();

    for (int o = t; o < 512; o += 256) {
        int c = o >> 6, d = o & 63;
        float s = bc1[c * 64 + d];
        for (int a = 0; a < 32; a++) s += tgl[a] * Wc1[(c * 32 + a) * 64 + d];
        hbuf[o] = gelu_exact(s);
    }
    __syncthreads();

    const int c = t >> 5, e = t & 31;
    float s = bc2[c * 32 + e];
    for (int d = 0; d < 64; d++) s += hbuf[c * 64 + d] * Wc2[(c * 64 + d) * 32 + e];
    pcb[t] = s;
    __syncthreads();

    float mean = 0.f;
    for (int k = 0; k < 32; k++) mean += pcb[c * 32 + k];
    mean *= (1.0f / 32.0f);
    float var = 0.f;
    for (int k = 0; k < 32; k++) { float dd = pcb[c * 32 + k] - mean; var += dd * dd; }
    var *= (1.0f / 32.0f);
    pw_out[b * PW_ + t] = (s - mean) * rsqrtf(var + 1e-5f) * g_c[c * 32 + e] + beta_c[c * 32 + e];
}

// ---------------- svd_ctx ----------------
__global__ __launch_bounds__(256) void ctx_kernel(
    const float* __restrict__ svd_raw, const float* __restrict__ W_svd,
    const float* __restrict__ b_svd, const float* __restrict__ g_svd,
    const float* __restrict__ beta_svd, float* __restrict__ ctx_out) {
    const int b = blockIdx.x, t = threadIdx.x;
    __shared__ float rawv[NR];
    __shared__ float red[4];
    if (t < NR) rawv[t] = svd_raw[b * NR + t];
    __syncthreads();
    float sv = b_svd[t];
    for (int r = 0; r < NR; r++) sv += rawv[r] * W_svd[r * PW_ + t];
    float mean = block_reduce_sum<4>(sv, red) * (1.0f / 256.0f);
    float dv = sv - mean;
    float var = block_reduce_sum<4>(dv * dv, red) * (1.0f / 256.0f);
    ctx_out[b * PW_ + t] = gelu_exact(dv * rsqrtf(var + 1e-5f) * g_svd[t] + beta_svd[t]);
}

// ---------------- cw + geo_out (f32) ----------------
__global__ __launch_bounds__(256) void cwgeo_kernel(
    const float* __restrict__ pw, const float* __restrict__ ctx,
    const float* __restrict__ geo_state, const float* __restrict__ W_mod,
    const float* __restrict__ b_mod, const float* __restrict__ geo_gate,
    const float* __restrict__ W_geo, const float* __restrict__ b_geo,
    const float* __restrict__ g_geo, const float* __restrict__ beta_geo,
    float* __restrict__ cw, float* __restrict__ out_geo) {
    const int b = blockIdx.x, t = threadIdx.x;
    __shared__ float mi[768];
    __shared__ float red[4];
    mi[t] = pw[b * PW_ + t];
    mi[256 + t] = ctx[b * PW_ + t];
    float geo = geo_state[b * PW_ + t];
    mi[512 + t] = geo;
    __syncthreads();

    float gg = b_geo[t];
    for (int q = 0; q < PW_; q++) gg += mi[q] * W_geo[q * PW_ + t];
    float gmean = block_reduce_sum<4>(gg, red) * (1.0f / 256.0f);
    float gdv = gg - gmean;
    float gvar = block_reduce_sum<4>(gdv * gdv, red) * (1.0f / 256.0f);
    float lnv = gdv * rsqrtf(gvar + 1e-5f) * g_geo[t] + beta_geo[t];
    out_geo[b * PW_ + t] = geo + sigmoidf_(geo_gate[t]) * lnv;

    for (int c = t; c < 512; c += 256) {
        float s = b_mod[c];
        for (int k = 0; k < 768; k++) s += mi[k] * W_mod[k * NC_ + c];
        cw[b * NC_ + c] = sigmoidf_(s);
    }
}

// ---------------- x_out(f32) = x(f32) * cw[b,c] ----------------
__global__ __launch_bounds__(256) void modulate_kernel(const float* __restrict__ x,
                                                       const float* __restrict__ cw,
                                                       float* __restrict__ out) {
    const int i4 = blockIdx.x * 256 + threadIdx.x;  // float4 index
    const float4* xp = (const float4*)x;
    float4 q = xp[i4];
    const float wv = cw[i4 >> 8];  // (i4*4)>>10 = b*512+c
    float4 o;
    o.x = q.x * wv; o.y = q.y * wv; o.z = q.z * wv; o.w = q.w * wv;
    ((float4*)out)[i4] = o;
}

extern "C" void kernel_launch(void* const* d_in, const int* in_sizes, int n_in,
                              void* d_out, int out_size, void* d_ws, size_t ws_size,
                              hipStream_t stream) {
    const float* x = (const float*)d_in[0];
    const float* geo_state = (const float*)d_in[1];
    const float* W_svd = (const float*)d_in[2];
    const float* b_svd = (const float*)d_in[3];
    const float* g_svd = (const float*)d_in[4];
    const float* beta_svd = (const float*)d_in[5];
    const float* W_emb = (const float*)d_in[6];
    const float* g_emb = (const float*)d_in[7];
    const float* beta_emb = (const float*)d_in[8];
    const float* anchors = (const float*)d_in[9];
    const float* Wc1 = (const float*)d_in[10];
    const float* bc1 = (const float*)d_in[11];
    const float* Wc2 = (const float*)d_in[12];
    const float* bc2 = (const float*)d_in[13];
    const float* g_c = (const float*)d_in[14];
    const float* beta_c = (const float*)d_in[15];
    const float* W_mod = (const float*)d_in[16];
    const float* b_mod = (const float*)d_in[17];
    const float* geo_gate = (const float*)d_in[18];
    const float* W_geo = (const float*)d_in[19];
    const float* b_geo = (const float*)d_in[20];
    const float* g_geo = (const float*)d_in[21];
    const float* beta_geo = (const float*)d_in[22];

    // d_out is FLOAT32: x_out = 16,777,216 f32 (67,108,864 B) + geo_out 8192 f32.
    // Scratch staged in d_out's first 28 MB; fully consumed before modulate
    // overwrites [0, 67,108,864) (stream-ordered). cw lives in d_ws.
    char* ob = (char*)d_out;
    u16* G = (u16*)(ob);                      // 16,777,216 B
    float* V = (float*)(ob + 16777216);       //  8,388,608 B -> 25,165,824
    float* cs = (float*)(ob + 25165824);      //     65,536 B -> 25,231,360
    float* svdraw = (float*)(ob + 25231360);  //      3,072 B -> 25,234,432
    float* tg = (float*)(ob + 25234432);      //      4,096 B -> 25,238,528
    float* pw = (float*)(ob + 25238528);      //     32,768 B -> 25,271,296
    float* ctxb = (float*)(ob + 25271296);    //     32,768 B -> 25,304,064
    float* cw = (float*)d_ws;                 //     65,536 B

    float* outx = (float*)d_out;
    float* outg = outx + 16777216;

    gram_kernel<<<dim3(16, 32), dim3(256), 0, stream>>>(x, G);
    colsum_kernel<<<dim3(4096), dim3(256), 0, stream>>>(x, cs);
    lanczos_kernel<<<dim3(32), dim3(1024), 0, stream>>>(G, V, svdraw);
    embgate_kernel<<<dim3(32), dim3(256), 0, stream>>>(cs, W_emb, g_emb, beta_emb, anchors, tg);
    mlp_kernel<<<dim3(32), dim3(256), 0, stream>>>(tg, Wc1, bc1, Wc2, bc2, g_c, beta_c, pw);
    ctx_kernel<<<dim3(32), dim3(256), 0, stream>>>(svdraw, W_svd, b_svd, g_svd, beta_svd, ctxb);
    cwgeo_kernel<<<dim3(32), dim3(256), 0, stream>>>(pw, ctxb, geo_state, W_mod, b_mod,
                                                     geo_gate, W_geo, b_geo, g_geo, beta_geo,
                                                     cw, outg);
    modulate_kernel<<<dim3(16384), dim3(256), 0, stream>>>(x, cw, outx);
}